// Round 9
// baseline (1859464.453 us; speedup 1.0000x reference)
//
#include <hip/hip_runtime.h>

#define CG_ITERS 30
#define PAP_OFF 32   // scal[0..30] = rs_i (f32) ; scal[32+it] = pAp_it (f32)

__device__ __forceinline__ float fadd32(float a, float b){ return __fadd_rn(a,b); }
__device__ __forceinline__ float fsub32(float a, float b){ return __fsub_rn(a,b); }
__device__ __forceinline__ float fmul32(float a, float b){ return __fmul_rn(a,b); }
__device__ __forceinline__ float fdiv32(float a, float b){ return __fdiv_rn(a,b); }

// ---- np-faithful per-edge force: f = Jx @ (p[e0]-p[e1]) ----
// numpy einsum 'eij,ej->ei' count=3 tail: switch fallthrough -> j DESCENDING (2,1,0).
__device__ __forceinline__ void edge_force(int2 e, int eidx,
                                           const float* __restrict__ pos,
                                           const float* __restrict__ rl,
                                           const float* __restrict__ p,
                                           float f[3]) {
    int i0 = 3 * e.x, i1 = 3 * e.y;
    float d[3], dh[3], dv[3];
    d[0] = fsub32(pos[i0 + 0], pos[i1 + 0]);
    d[1] = fsub32(pos[i0 + 1], pos[i1 + 1]);
    d[2] = fsub32(pos[i0 + 2], pos[i1 + 2]);
    // np.sum(d*d,-1): n=3 pairwise small branch = ascending sequential
    float ss = fadd32(fadd32(fmul32(d[0], d[0]), fmul32(d[1], d[1])), fmul32(d[2], d[2]));
    float l  = fadd32(__fsqrt_rn(ss), 1e-8f);
    dh[0] = fdiv32(d[0], l); dh[1] = fdiv32(d[1], l); dh[2] = fdiv32(d[2], l);
    float coef = fsub32(1.0f, fdiv32(rl[eidx], l));
    dv[0] = fsub32(p[i0 + 0], p[i1 + 0]);
    dv[1] = fsub32(p[i0 + 1], p[i1 + 1]);
    dv[2] = fsub32(p[i0 + 2], p[i1 + 2]);
    #pragma unroll
    for (int i = 0; i < 3; ++i) {
        float acc = 0.0f;
        #pragma unroll
        for (int j = 2; j >= 0; --j) {   // DESCENDING: numpy einsum tail order
            float dd = fmul32(dh[i], dh[j]);
            float t  = (i == j) ? fsub32(1.0f, dd) : fsub32(0.0f, dd);  // I3 - ddT
            float w  = fadd32(fmul32(coef, t), dd);   // coef*(I-ddT) + ddT
            float Jx = fmul32(-1000.0f, w);           // -KS * (...)
            acc = fadd32(acc, fmul32(Jx, dv[j]));
        }
        f[i] = acc;
    }
}

// ---- build: incidence CSR, deterministic, rebuilt every launch ----
__global__ void count_k(const int2* __restrict__ ed, int* __restrict__ cnt0,
                        int* __restrict__ cnt1, int ne) {
    int i = blockIdx.x * blockDim.x + threadIdx.x;
    if (i >= ne) return;
    int2 e = ed[i];
    atomicAdd(&cnt0[e.x], 1);
    atomicAdd(&cnt1[e.y], 1);
}

__global__ void scan_k(const int* __restrict__ cnt0, const int* __restrict__ cnt1,
                       int* __restrict__ segoff, int* __restrict__ split,
                       int* __restrict__ cur0, int* __restrict__ cur1, int nv) {
    __shared__ int lds[1024];
    int tid = threadIdx.x;
    int chunk = (nv + 1023) / 1024;
    int lo = tid * chunk;
    int hi = lo + chunk; if (hi > nv) hi = nv; if (lo > nv) lo = nv;
    int s = 0;
    for (int v = lo; v < hi; ++v) s += cnt0[v] + cnt1[v];
    lds[tid] = s;
    __syncthreads();
    for (int off = 1; off < 1024; off <<= 1) {
        int t = (tid >= off) ? lds[tid - off] : 0;
        __syncthreads();
        lds[tid] += t;
        __syncthreads();
    }
    int run = lds[tid] - s;  // exclusive
    for (int v = lo; v < hi; ++v) {
        int c0 = cnt0[v], c1 = cnt1[v];
        segoff[v] = run;
        split[v]  = run + c0;
        cur0[v]   = run;
        cur1[v]   = run + c0;
        run += c0 + c1;
    }
    if (tid == 1023) segoff[nv] = lds[1023];
}

__global__ void fill_k(const int2* __restrict__ ed, int* __restrict__ cur0,
                       int* __restrict__ cur1, int* __restrict__ inc, int ne) {
    int i = blockIdx.x * blockDim.x + threadIdx.x;
    if (i >= ne) return;
    int2 e = ed[i];
    int s0 = atomicAdd(&cur0[e.x], 1); inc[s0] = i;
    int s1 = atomicAdd(&cur1[e.y], 1); inc[s1] = i;
}

__global__ void sort_k(int* __restrict__ inc, const int* __restrict__ segoff,
                       const int* __restrict__ split, int nv) {
    int v = blockIdx.x * blockDim.x + threadIdx.x;
    if (v >= nv) return;
    int lo = segoff[v], mid = split[v], hi = segoff[v + 1];
    for (int a = lo + 1; a < mid; ++a) {
        int key = inc[a]; int b = a - 1;
        while (b >= lo && inc[b] > key) { inc[b + 1] = inc[b]; --b; }
        inc[b + 1] = key;
    }
    for (int a = mid + 1; a < hi; ++a) {
        int key = inc[a]; int b = a - 1;
        while (b >= mid && inc[b] > key) { inc[b + 1] = inc[b]; --b; }
        inc[b + 1] = key;
    }
}

// ---- CG kernels ----
__global__ void init_k(const float* __restrict__ rhs, float* __restrict__ x,
                       float* __restrict__ r, float* __restrict__ p, int n) {
    int j = blockIdx.x * blockDim.x + threadIdx.x;
    if (j >= n) return;
    float b = rhs[j];
    x[j] = 0.0f; r[j] = b; p[j] = b;
}

// matvec per vertex: np.add.at order (all e0-adds in edge order, then all e1-adds)
__global__ void mv_k(const int2* __restrict__ ed, const float* __restrict__ pos,
                     const float* __restrict__ rl, const float* __restrict__ p,
                     const float* __restrict__ mass, const int* __restrict__ inc,
                     const int* __restrict__ segoff, const int* __restrict__ split,
                     float* __restrict__ Ap, int nv) {
    int v = blockIdx.x * blockDim.x + threadIdx.x;
    if (v >= nv) return;
    int lo = segoff[v], mid = split[v], hi = segoff[v + 1];
    float a0 = 0.0f, a1 = 0.0f, a2 = 0.0f;
    for (int k = lo; k < mid; ++k) {
        int e = inc[k]; float f[3];
        edge_force(ed[e], e, pos, rl, p, f);
        a0 = fadd32(a0, f[0]); a1 = fadd32(a1, f[1]); a2 = fadd32(a2, f[2]);
    }
    for (int k = mid; k < hi; ++k) {
        int e = inc[k]; float f[3];
        edge_force(ed[e], e, pos, rl, p, f);
        a0 = fadd32(a0, -f[0]); a1 = fadd32(a1, -f[1]); a2 = fadd32(a2, -f[2]);
    }
    const float h2 = (float)(0.01 * 0.01);   // f32(H*H): f64 product, one cast
    int j = 3 * v; float m = mass[v];
    Ap[j + 0] = fsub32(fmul32(m, p[j + 0]), fmul32(h2, a0));
    Ap[j + 1] = fsub32(fmul32(m, p[j + 1]), fmul32(h2, a1));
    Ap[j + 2] = fsub32(fmul32(m, p[j + 2]), fmul32(h2, a2));
}

// np.vdot as numpy's no-CBLAS FLOAT_dot / OpenBLAS generic-C sdot:
//   float sum = 0; for (i=0..n-1) sum += x[i]*y[i];   // f32, ascending,
// separate mul+add (baseline x86-64 build: no FMA contraction).
// Single-thread serial chain: exactness over speed for this bisect round.
__global__ void dot_k(const float* __restrict__ x, const float* __restrict__ y,
                      float* __restrict__ out, int n) {
    if (threadIdx.x != 0 || blockIdx.x != 0) return;
    float s = 0.0f;
    for (int j = 0; j < n; ++j)
        s = fadd32(s, fmul32(x[j], y[j]));
    out[0] = s;
}

// numpy 1.x scalar-scalar promotion: alpha = f32( (f64)rs / ((f64)pAp + 1e-8) )
__global__ void xr_k(float* __restrict__ x, float* __restrict__ r,
                     const float* __restrict__ p, const float* __restrict__ Ap,
                     const float* __restrict__ scal, int it, int n) {
    int j = blockIdx.x * blockDim.x + threadIdx.x;
    if (j >= n) return;
    float alpha = (float)((double)scal[it] / ((double)scal[PAP_OFF + it] + 1e-8));
    x[j] = fadd32(x[j], fmul32(alpha, p[j]));
    r[j] = fsub32(r[j], fmul32(alpha, Ap[j]));
}

__global__ void p_k(const float* __restrict__ r, float* __restrict__ p,
                    const float* __restrict__ scal, int it, int n) {
    int j = blockIdx.x * blockDim.x + threadIdx.x;
    if (j >= n) return;
    float beta = (float)((double)scal[it + 1] / ((double)scal[it] + 1e-8));
    p[j] = fadd32(r[j], fmul32(beta, p[j]));
}

extern "C" void kernel_launch(void* const* d_in, const int* in_sizes, int n_in,
                              void* d_out, int out_size, void* d_ws, size_t ws_size,
                              hipStream_t stream) {
    const float* rhs  = (const float*)d_in[0];
    const float* pos  = (const float*)d_in[1];
    const float* mass = (const float*)d_in[2];
    const float* rl   = (const float*)d_in[3];
    const int2*  ed   = (const int2*)d_in[4];
    float* x = (float*)d_out;

    int NV = in_sizes[0] / 3;
    int NE = in_sizes[3];
    int n3 = NV * 3;

    char* w = (char*)d_ws;
    float* r    = (float*)w;  w += (size_t)n3 * sizeof(float);
    float* p    = (float*)w;  w += (size_t)n3 * sizeof(float);
    float* Ap   = (float*)w;  w += (size_t)n3 * sizeof(float);
    int*   inc  = (int*)w;    w += (size_t)2 * NE * sizeof(int);
    int*   cnt0 = (int*)w;    w += (size_t)NV * sizeof(int);
    int*   cnt1 = (int*)w;    w += (size_t)NV * sizeof(int);
    int*   segoff = (int*)w;  w += (size_t)(NV + 1) * sizeof(int);
    int*   split  = (int*)w;  w += (size_t)NV * sizeof(int);
    int*   cur0   = (int*)w;  w += (size_t)NV * sizeof(int);
    int*   cur1   = (int*)w;  w += (size_t)NV * sizeof(int);
    float* scal   = (float*)w;

    hipMemsetAsync(cnt0, 0, (size_t)2 * NV * sizeof(int), stream);  // cnt0+cnt1 adjacent

    const int tb = 256;
    int gE = (NE + tb - 1) / tb;
    int gV = (NV + tb - 1) / tb;
    int g3 = (n3 + tb - 1) / tb;

    count_k<<<gE, tb, 0, stream>>>(ed, cnt0, cnt1, NE);
    scan_k<<<1, 1024, 0, stream>>>(cnt0, cnt1, segoff, split, cur0, cur1, NV);
    fill_k<<<gE, tb, 0, stream>>>(ed, cur0, cur1, inc, NE);
    sort_k<<<gV, tb, 0, stream>>>(inc, segoff, split, NV);

    init_k<<<g3, tb, 0, stream>>>(rhs, x, r, p, n3);
    dot_k<<<1, 64, 0, stream>>>(rhs, rhs, &scal[0], n3);   // rs0 = vdot(b,b)

    for (int it = 0; it < CG_ITERS; ++it) {
        mv_k<<<gV, tb, 0, stream>>>(ed, pos, rl, p, mass, inc, segoff, split, Ap, NV);
        dot_k<<<1, 64, 0, stream>>>(p, Ap, &scal[PAP_OFF + it], n3);
        xr_k<<<g3, tb, 0, stream>>>(x, r, p, Ap, scal, it, n3);
        dot_k<<<1, 64, 0, stream>>>(r, r, &scal[it + 1], n3);
        p_k<<<g3, tb, 0, stream>>>(r, p, scal, it, n3);
    }
}

// Round 10
// 332869.531 us; speedup vs baseline: 5.5862x; 5.5862x over previous
//
#include <hip/hip_runtime.h>

#define CG_ITERS 30
#define PAP_OFF 32   // scal[0..30] = rs_i (f32) ; scal[32+it] = pAp_it (f32)

__device__ __forceinline__ float fadd32(float a, float b){ return __fadd_rn(a,b); }
__device__ __forceinline__ float fsub32(float a, float b){ return __fsub_rn(a,b); }
__device__ __forceinline__ float fmul32(float a, float b){ return __fmul_rn(a,b); }
__device__ __forceinline__ float fdiv32(float a, float b){ return __fdiv_rn(a,b); }

// ---- np-faithful per-edge force: f = Jx @ (p[e0]-p[e1]) ----
// numpy einsum 'eij,ej->ei' count=3 tail: switch fallthrough -> j DESCENDING (2,1,0).
__device__ __forceinline__ void edge_force(int2 e, int eidx,
                                           const float* __restrict__ pos,
                                           const float* __restrict__ rl,
                                           const float* __restrict__ p,
                                           float f[3]) {
    int i0 = 3 * e.x, i1 = 3 * e.y;
    float d[3], dh[3], dv[3];
    d[0] = fsub32(pos[i0 + 0], pos[i1 + 0]);
    d[1] = fsub32(pos[i0 + 1], pos[i1 + 1]);
    d[2] = fsub32(pos[i0 + 2], pos[i1 + 2]);
    // np.sum(d*d,-1): n=3 pairwise small branch = ascending sequential
    float ss = fadd32(fadd32(fmul32(d[0], d[0]), fmul32(d[1], d[1])), fmul32(d[2], d[2]));
    float l  = fadd32(__fsqrt_rn(ss), 1e-8f);
    dh[0] = fdiv32(d[0], l); dh[1] = fdiv32(d[1], l); dh[2] = fdiv32(d[2], l);
    float coef = fsub32(1.0f, fdiv32(rl[eidx], l));
    dv[0] = fsub32(p[i0 + 0], p[i1 + 0]);
    dv[1] = fsub32(p[i0 + 1], p[i1 + 1]);
    dv[2] = fsub32(p[i0 + 2], p[i1 + 2]);
    #pragma unroll
    for (int i = 0; i < 3; ++i) {
        float acc = 0.0f;
        #pragma unroll
        for (int j = 2; j >= 0; --j) {   // DESCENDING: numpy einsum tail order
            float dd = fmul32(dh[i], dh[j]);
            float t  = (i == j) ? fsub32(1.0f, dd) : fsub32(0.0f, dd);  // I3 - ddT
            float w  = fadd32(fmul32(coef, t), dd);   // coef*(I-ddT) + ddT
            float Jx = fmul32(-1000.0f, w);           // -KS * (...)
            acc = fadd32(acc, fmul32(Jx, dv[j]));
        }
        f[i] = acc;
    }
}

// ---- build: incidence CSR, deterministic, rebuilt every launch ----
__global__ void count_k(const int2* __restrict__ ed, int* __restrict__ cnt0,
                        int* __restrict__ cnt1, int ne) {
    int i = blockIdx.x * blockDim.x + threadIdx.x;
    if (i >= ne) return;
    int2 e = ed[i];
    atomicAdd(&cnt0[e.x], 1);
    atomicAdd(&cnt1[e.y], 1);
}

__global__ void scan_k(const int* __restrict__ cnt0, const int* __restrict__ cnt1,
                       int* __restrict__ segoff, int* __restrict__ split,
                       int* __restrict__ cur0, int* __restrict__ cur1, int nv) {
    __shared__ int lds[1024];
    int tid = threadIdx.x;
    int chunk = (nv + 1023) / 1024;
    int lo = tid * chunk;
    int hi = lo + chunk; if (hi > nv) hi = nv; if (lo > nv) lo = nv;
    int s = 0;
    for (int v = lo; v < hi; ++v) s += cnt0[v] + cnt1[v];
    lds[tid] = s;
    __syncthreads();
    for (int off = 1; off < 1024; off <<= 1) {
        int t = (tid >= off) ? lds[tid - off] : 0;
        __syncthreads();
        lds[tid] += t;
        __syncthreads();
    }
    int run = lds[tid] - s;  // exclusive
    for (int v = lo; v < hi; ++v) {
        int c0 = cnt0[v], c1 = cnt1[v];
        segoff[v] = run;
        split[v]  = run + c0;
        cur0[v]   = run;
        cur1[v]   = run + c0;
        run += c0 + c1;
    }
    if (tid == 1023) segoff[nv] = lds[1023];
}

__global__ void fill_k(const int2* __restrict__ ed, int* __restrict__ cur0,
                       int* __restrict__ cur1, int* __restrict__ inc, int ne) {
    int i = blockIdx.x * blockDim.x + threadIdx.x;
    if (i >= ne) return;
    int2 e = ed[i];
    int s0 = atomicAdd(&cur0[e.x], 1); inc[s0] = i;
    int s1 = atomicAdd(&cur1[e.y], 1); inc[s1] = i;
}

__global__ void sort_k(int* __restrict__ inc, const int* __restrict__ segoff,
                       const int* __restrict__ split, int nv) {
    int v = blockIdx.x * blockDim.x + threadIdx.x;
    if (v >= nv) return;
    int lo = segoff[v], mid = split[v], hi = segoff[v + 1];
    for (int a = lo + 1; a < mid; ++a) {
        int key = inc[a]; int b = a - 1;
        while (b >= lo && inc[b] > key) { inc[b + 1] = inc[b]; --b; }
        inc[b + 1] = key;
    }
    for (int a = mid + 1; a < hi; ++a) {
        int key = inc[a]; int b = a - 1;
        while (b >= mid && inc[b] > key) { inc[b + 1] = inc[b]; --b; }
        inc[b + 1] = key;
    }
}

// ---- CG kernels ----
// init: x=0, r=p=b, prod = b*b (for rs0 chain)
__global__ void init_k(const float* __restrict__ rhs, float* __restrict__ x,
                       float* __restrict__ r, float* __restrict__ p,
                       float* __restrict__ prod, int n) {
    int j = blockIdx.x * blockDim.x + threadIdx.x;
    if (j >= n) return;
    float b = rhs[j];
    x[j] = 0.0f; r[j] = b; p[j] = b;
    prod[j] = fmul32(b, b);
}

// matvec per vertex (np.add.at order) + prod = p*Ap (for pAp chain)
__global__ void mv_k(const int2* __restrict__ ed, const float* __restrict__ pos,
                     const float* __restrict__ rl, const float* __restrict__ p,
                     const float* __restrict__ mass, const int* __restrict__ inc,
                     const int* __restrict__ segoff, const int* __restrict__ split,
                     float* __restrict__ Ap, float* __restrict__ prod, int nv) {
    int v = blockIdx.x * blockDim.x + threadIdx.x;
    if (v >= nv) return;
    int lo = segoff[v], mid = split[v], hi = segoff[v + 1];
    float a0 = 0.0f, a1 = 0.0f, a2 = 0.0f;
    for (int k = lo; k < mid; ++k) {
        int e = inc[k]; float f[3];
        edge_force(ed[e], e, pos, rl, p, f);
        a0 = fadd32(a0, f[0]); a1 = fadd32(a1, f[1]); a2 = fadd32(a2, f[2]);
    }
    for (int k = mid; k < hi; ++k) {
        int e = inc[k]; float f[3];
        edge_force(ed[e], e, pos, rl, p, f);
        a0 = fadd32(a0, -f[0]); a1 = fadd32(a1, -f[1]); a2 = fadd32(a2, -f[2]);
    }
    const float h2 = (float)(0.01 * 0.01);   // f32(H*H): f64 product, one cast
    int j = 3 * v; float m = mass[v];
    float p0 = p[j], p1 = p[j + 1], p2 = p[j + 2];
    float A0 = fsub32(fmul32(m, p0), fmul32(h2, a0));
    float A1 = fsub32(fmul32(m, p1), fmul32(h2, a1));
    float A2 = fsub32(fmul32(m, p2), fmul32(h2, a2));
    Ap[j + 0] = A0; Ap[j + 1] = A1; Ap[j + 2] = A2;
    prod[j + 0] = fmul32(p0, A0);
    prod[j + 1] = fmul32(p1, A1);
    prod[j + 2] = fmul32(p2, A2);
}

// Serial sequential-f32 add chain over precomputed products — numpy's
// no-CBLAS FLOAT_dot: float sum=0; for i: sum += x[i]*y[i];  (ascending).
// Products staged by parallel kernels; here only dependent fadds remain
// (~4 cyc/elem), float4 loads pipelined ahead by the compiler.
__global__ void chain_k(const float* __restrict__ prod, float* __restrict__ out, int n) {
    if (threadIdx.x != 0 || blockIdx.x != 0) return;
    const float4* p4 = (const float4*)prod;
    int n4 = n >> 2;
    float s = 0.0f;
    int j = 0;
    for (; j + 8 <= n4; j += 8) {   // 32 elems/iter; 600000 = 32*18750 exact
        float4 v0 = p4[j + 0], v1 = p4[j + 1], v2 = p4[j + 2], v3 = p4[j + 3];
        float4 v4 = p4[j + 4], v5 = p4[j + 5], v6 = p4[j + 6], v7 = p4[j + 7];
        s = fadd32(s, v0.x); s = fadd32(s, v0.y); s = fadd32(s, v0.z); s = fadd32(s, v0.w);
        s = fadd32(s, v1.x); s = fadd32(s, v1.y); s = fadd32(s, v1.z); s = fadd32(s, v1.w);
        s = fadd32(s, v2.x); s = fadd32(s, v2.y); s = fadd32(s, v2.z); s = fadd32(s, v2.w);
        s = fadd32(s, v3.x); s = fadd32(s, v3.y); s = fadd32(s, v3.z); s = fadd32(s, v3.w);
        s = fadd32(s, v4.x); s = fadd32(s, v4.y); s = fadd32(s, v4.z); s = fadd32(s, v4.w);
        s = fadd32(s, v5.x); s = fadd32(s, v5.y); s = fadd32(s, v5.z); s = fadd32(s, v5.w);
        s = fadd32(s, v6.x); s = fadd32(s, v6.y); s = fadd32(s, v6.z); s = fadd32(s, v6.w);
        s = fadd32(s, v7.x); s = fadd32(s, v7.y); s = fadd32(s, v7.z); s = fadd32(s, v7.w);
    }
    for (; j < n4; ++j) {
        float4 v = p4[j];
        s = fadd32(s, v.x); s = fadd32(s, v.y); s = fadd32(s, v.z); s = fadd32(s, v.w);
    }
    for (int k = n & ~3; k < n; ++k) s = fadd32(s, prod[k]);
    out[0] = s;
}

// x += alpha p ; r -= alpha Ap ; prod = r_new*r_new (for rs chain)
__global__ void xr_k(float* __restrict__ x, float* __restrict__ r,
                     const float* __restrict__ p, const float* __restrict__ Ap,
                     float* __restrict__ prod, const float* __restrict__ scal,
                     int it, int n) {
    int j = blockIdx.x * blockDim.x + threadIdx.x;
    if (j >= n) return;
    float alpha = (float)((double)scal[it] / ((double)scal[PAP_OFF + it] + 1e-8));
    x[j] = fadd32(x[j], fmul32(alpha, p[j]));
    float rn = fsub32(r[j], fmul32(alpha, Ap[j]));
    r[j] = rn;
    prod[j] = fmul32(rn, rn);
}

__global__ void p_k(const float* __restrict__ r, float* __restrict__ p,
                    const float* __restrict__ scal, int it, int n) {
    int j = blockIdx.x * blockDim.x + threadIdx.x;
    if (j >= n) return;
    float beta = (float)((double)scal[it + 1] / ((double)scal[it] + 1e-8));
    p[j] = fadd32(r[j], fmul32(beta, p[j]));
}

extern "C" void kernel_launch(void* const* d_in, const int* in_sizes, int n_in,
                              void* d_out, int out_size, void* d_ws, size_t ws_size,
                              hipStream_t stream) {
    const float* rhs  = (const float*)d_in[0];
    const float* pos  = (const float*)d_in[1];
    const float* mass = (const float*)d_in[2];
    const float* rl   = (const float*)d_in[3];
    const int2*  ed   = (const int2*)d_in[4];
    float* x = (float*)d_out;

    int NV = in_sizes[0] / 3;
    int NE = in_sizes[3];
    int n3 = NV * 3;

    char* w = (char*)d_ws;
    float* r    = (float*)w;  w += (size_t)n3 * sizeof(float);
    float* p    = (float*)w;  w += (size_t)n3 * sizeof(float);
    float* Ap   = (float*)w;  w += (size_t)n3 * sizeof(float);
    float* prod = (float*)w;  w += (size_t)n3 * sizeof(float);
    int*   inc  = (int*)w;    w += (size_t)2 * NE * sizeof(int);
    int*   cnt0 = (int*)w;    w += (size_t)NV * sizeof(int);
    int*   cnt1 = (int*)w;    w += (size_t)NV * sizeof(int);
    int*   segoff = (int*)w;  w += (size_t)(NV + 1) * sizeof(int);
    int*   split  = (int*)w;  w += (size_t)NV * sizeof(int);
    int*   cur0   = (int*)w;  w += (size_t)NV * sizeof(int);
    int*   cur1   = (int*)w;  w += (size_t)NV * sizeof(int);
    float* scal   = (float*)w;

    hipMemsetAsync(cnt0, 0, (size_t)2 * NV * sizeof(int), stream);  // cnt0+cnt1 adjacent

    const int tb = 256;
    int gE = (NE + tb - 1) / tb;
    int gV = (NV + tb - 1) / tb;
    int g3 = (n3 + tb - 1) / tb;

    count_k<<<gE, tb, 0, stream>>>(ed, cnt0, cnt1, NE);
    scan_k<<<1, 1024, 0, stream>>>(cnt0, cnt1, segoff, split, cur0, cur1, NV);
    fill_k<<<gE, tb, 0, stream>>>(ed, cur0, cur1, inc, NE);
    sort_k<<<gV, tb, 0, stream>>>(inc, segoff, split, NV);

    init_k<<<g3, tb, 0, stream>>>(rhs, x, r, p, prod, n3);
    chain_k<<<1, 64, 0, stream>>>(prod, &scal[0], n3);   // rs0 = vdot(b,b)

    for (int it = 0; it < CG_ITERS; ++it) {
        mv_k<<<gV, tb, 0, stream>>>(ed, pos, rl, p, mass, inc, segoff, split, Ap, prod, NV);
        chain_k<<<1, 64, 0, stream>>>(prod, &scal[PAP_OFF + it], n3);
        xr_k<<<g3, tb, 0, stream>>>(x, r, p, Ap, prod, scal, it, n3);
        chain_k<<<1, 64, 0, stream>>>(prod, &scal[it + 1], n3);
        p_k<<<g3, tb, 0, stream>>>(r, p, scal, it, n3);
    }
}

// Round 11
// 136133.398 us; speedup vs baseline: 13.6591x; 2.4452x over previous
//
#include <hip/hip_runtime.h>

#define CG_ITERS 30
#define PAP_OFF 32   // scal[0..30] = rs_i (f32) ; scal[32+it] = pAp_it (f32)
#define TILE 8192
#define CHAIN_TB 256

__device__ __forceinline__ float fadd32(float a, float b){ return __fadd_rn(a,b); }
__device__ __forceinline__ float fsub32(float a, float b){ return __fsub_rn(a,b); }
__device__ __forceinline__ float fmul32(float a, float b){ return __fmul_rn(a,b); }
__device__ __forceinline__ float fdiv32(float a, float b){ return __fdiv_rn(a,b); }

// ---- np-faithful per-edge force: f = Jx @ (p[e0]-p[e1]) ----
// numpy einsum 'eij,ej->ei' count=3 tail: switch fallthrough -> j DESCENDING (2,1,0).
__device__ __forceinline__ void edge_force(int2 e, int eidx,
                                           const float* __restrict__ pos,
                                           const float* __restrict__ rl,
                                           const float* __restrict__ p,
                                           float f[3]) {
    int i0 = 3 * e.x, i1 = 3 * e.y;
    float d[3], dh[3], dv[3];
    d[0] = fsub32(pos[i0 + 0], pos[i1 + 0]);
    d[1] = fsub32(pos[i0 + 1], pos[i1 + 1]);
    d[2] = fsub32(pos[i0 + 2], pos[i1 + 2]);
    // np.sum(d*d,-1): n=3 pairwise small branch = ascending sequential
    float ss = fadd32(fadd32(fmul32(d[0], d[0]), fmul32(d[1], d[1])), fmul32(d[2], d[2]));
    float l  = fadd32(__fsqrt_rn(ss), 1e-8f);
    dh[0] = fdiv32(d[0], l); dh[1] = fdiv32(d[1], l); dh[2] = fdiv32(d[2], l);
    float coef = fsub32(1.0f, fdiv32(rl[eidx], l));
    dv[0] = fsub32(p[i0 + 0], p[i1 + 0]);
    dv[1] = fsub32(p[i0 + 1], p[i1 + 1]);
    dv[2] = fsub32(p[i0 + 2], p[i1 + 2]);
    #pragma unroll
    for (int i = 0; i < 3; ++i) {
        float acc = 0.0f;
        #pragma unroll
        for (int j = 2; j >= 0; --j) {   // DESCENDING: numpy einsum tail order
            float dd = fmul32(dh[i], dh[j]);
            float t  = (i == j) ? fsub32(1.0f, dd) : fsub32(0.0f, dd);  // I3 - ddT
            float w  = fadd32(fmul32(coef, t), dd);   // coef*(I-ddT) + ddT
            float Jx = fmul32(-1000.0f, w);           // -KS * (...)
            acc = fadd32(acc, fmul32(Jx, dv[j]));
        }
        f[i] = acc;
    }
}

// ---- build: incidence CSR, deterministic, rebuilt every launch ----
__global__ void count_k(const int2* __restrict__ ed, int* __restrict__ cnt0,
                        int* __restrict__ cnt1, int ne) {
    int i = blockIdx.x * blockDim.x + threadIdx.x;
    if (i >= ne) return;
    int2 e = ed[i];
    atomicAdd(&cnt0[e.x], 1);
    atomicAdd(&cnt1[e.y], 1);
}

__global__ void scan_k(const int* __restrict__ cnt0, const int* __restrict__ cnt1,
                       int* __restrict__ segoff, int* __restrict__ split,
                       int* __restrict__ cur0, int* __restrict__ cur1, int nv) {
    __shared__ int lds[1024];
    int tid = threadIdx.x;
    int chunk = (nv + 1023) / 1024;
    int lo = tid * chunk;
    int hi = lo + chunk; if (hi > nv) hi = nv; if (lo > nv) lo = nv;
    int s = 0;
    for (int v = lo; v < hi; ++v) s += cnt0[v] + cnt1[v];
    lds[tid] = s;
    __syncthreads();
    for (int off = 1; off < 1024; off <<= 1) {
        int t = (tid >= off) ? lds[tid - off] : 0;
        __syncthreads();
        lds[tid] += t;
        __syncthreads();
    }
    int run = lds[tid] - s;  // exclusive
    for (int v = lo; v < hi; ++v) {
        int c0 = cnt0[v], c1 = cnt1[v];
        segoff[v] = run;
        split[v]  = run + c0;
        cur0[v]   = run;
        cur1[v]   = run + c0;
        run += c0 + c1;
    }
    if (tid == 1023) segoff[nv] = lds[1023];
}

__global__ void fill_k(const int2* __restrict__ ed, int* __restrict__ cur0,
                       int* __restrict__ cur1, int* __restrict__ inc, int ne) {
    int i = blockIdx.x * blockDim.x + threadIdx.x;
    if (i >= ne) return;
    int2 e = ed[i];
    int s0 = atomicAdd(&cur0[e.x], 1); inc[s0] = i;
    int s1 = atomicAdd(&cur1[e.y], 1); inc[s1] = i;
}

__global__ void sort_k(int* __restrict__ inc, const int* __restrict__ segoff,
                       const int* __restrict__ split, int nv) {
    int v = blockIdx.x * blockDim.x + threadIdx.x;
    if (v >= nv) return;
    int lo = segoff[v], mid = split[v], hi = segoff[v + 1];
    for (int a = lo + 1; a < mid; ++a) {
        int key = inc[a]; int b = a - 1;
        while (b >= lo && inc[b] > key) { inc[b + 1] = inc[b]; --b; }
        inc[b + 1] = key;
    }
    for (int a = mid + 1; a < hi; ++a) {
        int key = inc[a]; int b = a - 1;
        while (b >= mid && inc[b] > key) { inc[b + 1] = inc[b]; --b; }
        inc[b + 1] = key;
    }
}

// ---- CG kernels ----
// init: x=0, r=p=b, prod = b*b (for rs0 chain)
__global__ void init_k(const float* __restrict__ rhs, float* __restrict__ x,
                       float* __restrict__ r, float* __restrict__ p,
                       float* __restrict__ prod, int n) {
    int j = blockIdx.x * blockDim.x + threadIdx.x;
    if (j >= n) return;
    float b = rhs[j];
    x[j] = 0.0f; r[j] = b; p[j] = b;
    prod[j] = fmul32(b, b);
}

// matvec per vertex (np.add.at order) + prod = p*Ap (for pAp chain)
__global__ void mv_k(const int2* __restrict__ ed, const float* __restrict__ pos,
                     const float* __restrict__ rl, const float* __restrict__ p,
                     const float* __restrict__ mass, const int* __restrict__ inc,
                     const int* __restrict__ segoff, const int* __restrict__ split,
                     float* __restrict__ Ap, float* __restrict__ prod, int nv) {
    int v = blockIdx.x * blockDim.x + threadIdx.x;
    if (v >= nv) return;
    int lo = segoff[v], mid = split[v], hi = segoff[v + 1];
    float a0 = 0.0f, a1 = 0.0f, a2 = 0.0f;
    for (int k = lo; k < mid; ++k) {
        int e = inc[k]; float f[3];
        edge_force(ed[e], e, pos, rl, p, f);
        a0 = fadd32(a0, f[0]); a1 = fadd32(a1, f[1]); a2 = fadd32(a2, f[2]);
    }
    for (int k = mid; k < hi; ++k) {
        int e = inc[k]; float f[3];
        edge_force(ed[e], e, pos, rl, p, f);
        a0 = fadd32(a0, -f[0]); a1 = fadd32(a1, -f[1]); a2 = fadd32(a2, -f[2]);
    }
    const float h2 = (float)(0.01 * 0.01);   // f32(H*H): f64 product, one cast
    int j = 3 * v; float m = mass[v];
    float p0 = p[j], p1 = p[j + 1], p2 = p[j + 2];
    float A0 = fsub32(fmul32(m, p0), fmul32(h2, a0));
    float A1 = fsub32(fmul32(m, p1), fmul32(h2, a1));
    float A2 = fsub32(fmul32(m, p2), fmul32(h2, a2));
    Ap[j + 0] = A0; Ap[j + 1] = A1; Ap[j + 2] = A2;
    prod[j + 0] = fmul32(p0, A0);
    prod[j + 1] = fmul32(p1, A1);
    prod[j + 2] = fmul32(p2, A2);
}

// Serial sequential-f32 add chain (numpy no-CBLAS FLOAT_dot order) with
// producer-consumer LDS double-buffer: 256 threads stage tile t+1 from HBM
// while thread 0 runs the dependent fadd chain over tile t from LDS.
// Values and order identical to numpy's: float sum=0; for i: sum += prod[i].
__global__ void chain_k(const float* __restrict__ prod, float* __restrict__ out, int n) {
    __shared__ float buf[2][TILE];
    int tid = threadIdx.x;
    int ntiles = (n + TILE - 1) / TILE;
    // preload tile 0
    {
        int lim = (TILE < n) ? TILE : n;
        for (int i = tid; i < lim; i += CHAIN_TB) buf[0][i] = prod[i];
    }
    __syncthreads();
    float s = 0.0f;
    for (int t = 0; t < ntiles; ++t) {
        if (t + 1 < ntiles) {                 // stage next tile while chaining
            int base = (t + 1) * TILE;
            int lim = n - base; if (lim > TILE) lim = TILE;
            float* dst = buf[(t + 1) & 1];
            for (int i = tid; i < lim; i += CHAIN_TB) dst[i] = prod[base + i];
        }
        if (tid == 0) {
            const float* b = buf[t & 1];
            int cnt = n - t * TILE; if (cnt > TILE) cnt = TILE;
            const float4* b4 = (const float4*)b;
            int c4 = cnt >> 2;
            int i = 0;
            for (; i + 8 <= c4; i += 8) {     // 32 elems/iter, ds_read_b128 x8
                float4 v0 = b4[i + 0], v1 = b4[i + 1], v2 = b4[i + 2], v3 = b4[i + 3];
                float4 v4 = b4[i + 4], v5 = b4[i + 5], v6 = b4[i + 6], v7 = b4[i + 7];
                s = fadd32(s, v0.x); s = fadd32(s, v0.y); s = fadd32(s, v0.z); s = fadd32(s, v0.w);
                s = fadd32(s, v1.x); s = fadd32(s, v1.y); s = fadd32(s, v1.z); s = fadd32(s, v1.w);
                s = fadd32(s, v2.x); s = fadd32(s, v2.y); s = fadd32(s, v2.z); s = fadd32(s, v2.w);
                s = fadd32(s, v3.x); s = fadd32(s, v3.y); s = fadd32(s, v3.z); s = fadd32(s, v3.w);
                s = fadd32(s, v4.x); s = fadd32(s, v4.y); s = fadd32(s, v4.z); s = fadd32(s, v4.w);
                s = fadd32(s, v5.x); s = fadd32(s, v5.y); s = fadd32(s, v5.z); s = fadd32(s, v5.w);
                s = fadd32(s, v6.x); s = fadd32(s, v6.y); s = fadd32(s, v6.z); s = fadd32(s, v6.w);
                s = fadd32(s, v7.x); s = fadd32(s, v7.y); s = fadd32(s, v7.z); s = fadd32(s, v7.w);
            }
            for (; i < c4; ++i) {
                float4 v = b4[i];
                s = fadd32(s, v.x); s = fadd32(s, v.y); s = fadd32(s, v.z); s = fadd32(s, v.w);
            }
            for (int k = c4 << 2; k < cnt; ++k) s = fadd32(s, b[k]);
        }
        __syncthreads();   // tile t+1 staged AND thread0 done with buf[t&1]
    }
    if (tid == 0) out[0] = s;
}

// x += alpha p ; r -= alpha Ap ; prod = r_new*r_new (for rs chain)
// numpy 1.x scalar-scalar promotion: alpha = f32( (f64)rs / ((f64)pAp + 1e-8) )
__global__ void xr_k(float* __restrict__ x, float* __restrict__ r,
                     const float* __restrict__ p, const float* __restrict__ Ap,
                     float* __restrict__ prod, const float* __restrict__ scal,
                     int it, int n) {
    int j = blockIdx.x * blockDim.x + threadIdx.x;
    if (j >= n) return;
    float alpha = (float)((double)scal[it] / ((double)scal[PAP_OFF + it] + 1e-8));
    x[j] = fadd32(x[j], fmul32(alpha, p[j]));
    float rn = fsub32(r[j], fmul32(alpha, Ap[j]));
    r[j] = rn;
    prod[j] = fmul32(rn, rn);
}

__global__ void p_k(const float* __restrict__ r, float* __restrict__ p,
                    const float* __restrict__ scal, int it, int n) {
    int j = blockIdx.x * blockDim.x + threadIdx.x;
    if (j >= n) return;
    float beta = (float)((double)scal[it + 1] / ((double)scal[it] + 1e-8));
    p[j] = fadd32(r[j], fmul32(beta, p[j]));
}

extern "C" void kernel_launch(void* const* d_in, const int* in_sizes, int n_in,
                              void* d_out, int out_size, void* d_ws, size_t ws_size,
                              hipStream_t stream) {
    const float* rhs  = (const float*)d_in[0];
    const float* pos  = (const float*)d_in[1];
    const float* mass = (const float*)d_in[2];
    const float* rl   = (const float*)d_in[3];
    const int2*  ed   = (const int2*)d_in[4];
    float* x = (float*)d_out;

    int NV = in_sizes[0] / 3;
    int NE = in_sizes[3];
    int n3 = NV * 3;

    char* w = (char*)d_ws;
    float* r    = (float*)w;  w += (size_t)n3 * sizeof(float);
    float* p    = (float*)w;  w += (size_t)n3 * sizeof(float);
    float* Ap   = (float*)w;  w += (size_t)n3 * sizeof(float);
    float* prod = (float*)w;  w += (size_t)n3 * sizeof(float);
    int*   inc  = (int*)w;    w += (size_t)2 * NE * sizeof(int);
    int*   cnt0 = (int*)w;    w += (size_t)NV * sizeof(int);
    int*   cnt1 = (int*)w;    w += (size_t)NV * sizeof(int);
    int*   segoff = (int*)w;  w += (size_t)(NV + 1) * sizeof(int);
    int*   split  = (int*)w;  w += (size_t)NV * sizeof(int);
    int*   cur0   = (int*)w;  w += (size_t)NV * sizeof(int);
    int*   cur1   = (int*)w;  w += (size_t)NV * sizeof(int);
    float* scal   = (float*)w;

    hipMemsetAsync(cnt0, 0, (size_t)2 * NV * sizeof(int), stream);  // cnt0+cnt1 adjacent

    const int tb = 256;
    int gE = (NE + tb - 1) / tb;
    int gV = (NV + tb - 1) / tb;
    int g3 = (n3 + tb - 1) / tb;

    count_k<<<gE, tb, 0, stream>>>(ed, cnt0, cnt1, NE);
    scan_k<<<1, 1024, 0, stream>>>(cnt0, cnt1, segoff, split, cur0, cur1, NV);
    fill_k<<<gE, tb, 0, stream>>>(ed, cur0, cur1, inc, NE);
    sort_k<<<gV, tb, 0, stream>>>(inc, segoff, split, NV);

    init_k<<<g3, tb, 0, stream>>>(rhs, x, r, p, prod, n3);
    chain_k<<<1, CHAIN_TB, 0, stream>>>(prod, &scal[0], n3);   // rs0 = vdot(b,b)

    for (int it = 0; it < CG_ITERS; ++it) {
        mv_k<<<gV, tb, 0, stream>>>(ed, pos, rl, p, mass, inc, segoff, split, Ap, prod, NV);
        chain_k<<<1, CHAIN_TB, 0, stream>>>(prod, &scal[PAP_OFF + it], n3);
        xr_k<<<g3, tb, 0, stream>>>(x, r, p, Ap, prod, scal, it, n3);
        chain_k<<<1, CHAIN_TB, 0, stream>>>(prod, &scal[it + 1], n3);
        p_k<<<g3, tb, 0, stream>>>(r, p, scal, it, n3);
    }
}